// Round 8
// baseline (1977.742 us; speedup 1.0000x reference)
//
#include <hip/hip_runtime.h>

typedef float f32x4 __attribute__((ext_vector_type(4)));
typedef __bf16 bf16x8 __attribute__((ext_vector_type(8)));

#define NROWS 16384   // B*S
#define SEQ   4096
#define EMBD  512
#define MLPD  2048

__device__ inline float gelu_tanh(float x) {
    float t = 0.7978845608028654f * (x + 0.044715f * x * x * x);
    float e = __expf(2.f * t);
    float th = 1.f - 2.f / (1.f + e);
    return 0.5f * x * (1.f + th);
}

__device__ inline void nt_store_bf16(__bf16 v, __bf16* p) {
    __builtin_nontemporal_store(__builtin_bit_cast(unsigned short, v), (unsigned short*)p);
}

// direct global->LDS 16B DMA; LDS dest must be linear in lane order
#define GLOAD16(gp, lp)                                                        \
    __builtin_amdgcn_global_load_lds(                                          \
        (const __attribute__((address_space(1))) void*)(gp),                   \
        (__attribute__((address_space(3))) void*)(lp), 16, 0, 0)

// ---------------- positional table: pos[s][512] ----------------
__global__ void pos_kernel(float* __restrict__ pos) {
    int i = blockIdx.x * 256 + threadIdx.x;        // 4096*256
    int s = i >> 8, j = i & 255;
    float div = __expf((float)j * (-2.f * 9.210340371976184f / 512.f));
    float a = (float)s * div;
    pos[(size_t)s * 512 + 2 * j]     = sinf(a);
    pos[(size_t)s * 512 + 2 * j + 1] = cosf(a);
}

// ---------------- embedding gather + pos add ----------------
__global__ void embed_kernel(const int* __restrict__ tokens,
                             const float* __restrict__ embed,
                             const float* __restrict__ pos,
                             float* __restrict__ x) {
    int row = blockIdx.x;            // 16384
    int t = threadIdx.x;             // 128
    int s = row & (SEQ - 1);
    int tok = tokens[row];
    f32x4 e = *(const f32x4*)(embed + (size_t)tok * 512 + t * 4);
    f32x4 p = *(const f32x4*)(pos + (size_t)s * 512 + t * 4);
    e += p;
    *(f32x4*)(x + (size_t)row * 512 + t * 4) = e;
}

// ---------------- transpose fp32 [K][N] -> bf16 [N][K], batched over z ----------------
__global__ void transpose_bf16(const float* __restrict__ in, __bf16* __restrict__ out,
                               int K, int N, size_t in_lstride, size_t out_lstride) {
    __shared__ float tile[32][33];
    in  += (size_t)blockIdx.z * in_lstride;
    out += (size_t)blockIdx.z * out_lstride;
    int n0 = blockIdx.x * 32, k0 = blockIdx.y * 32;
    int tx = threadIdx.x, ty = threadIdx.y;   // 32 x 8
    #pragma unroll
    for (int i = 0; i < 32; i += 8)
        tile[ty + i][tx] = in[(size_t)(k0 + ty + i) * N + n0 + tx];
    __syncthreads();
    #pragma unroll
    for (int i = 0; i < 32; i += 8)
        out[(size_t)(n0 + ty + i) * K + k0 + tx] = (__bf16)tile[tx][ty + i];
}

// ---------------- LayerNorm (one wave per 512-row) ----------------
template<int OUTBF>
__global__ __launch_bounds__(256) void ln_kernel(
    const float* __restrict__ x, const float* __restrict__ gamma,
    const float* __restrict__ beta, __bf16* __restrict__ outb,
    float* __restrict__ outf) {
    int lane = threadIdx.x & 63;
    size_t row = (size_t)blockIdx.x * 4 + (threadIdx.x >> 6);
    const float* xr = x + row * 512 + lane * 8;
    f32x4 v0 = *(const f32x4*)xr;
    f32x4 v1 = *(const f32x4*)(xr + 4);
    float sum = (v0[0] + v0[1]) + (v0[2] + v0[3]) + (v1[0] + v1[1]) + (v1[2] + v1[3]);
    #pragma unroll
    for (int off = 32; off; off >>= 1) sum += __shfl_xor(sum, off);
    float mu = sum * (1.f / 512.f);
    float vs = 0.f;
    #pragma unroll
    for (int j = 0; j < 4; j++) {
        float d0 = v0[j] - mu; vs += d0 * d0;
        float d1 = v1[j] - mu; vs += d1 * d1;
    }
    #pragma unroll
    for (int off = 32; off; off >>= 1) vs += __shfl_xor(vs, off);
    float inv = rsqrtf(vs * (1.f / 512.f) + 1e-6f);
    const float* gp = gamma + lane * 8;
    const float* bp = beta + lane * 8;
    f32x4 g0 = *(const f32x4*)gp, g1 = *(const f32x4*)(gp + 4);
    f32x4 bb0 = *(const f32x4*)bp, bb1 = *(const f32x4*)(bp + 4);
    float o[8];
    #pragma unroll
    for (int j = 0; j < 4; j++) {
        o[j]     = (v0[j] - mu) * inv * g0[j] + bb0[j];
        o[4 + j] = (v1[j] - mu) * inv * g1[j] + bb1[j];
    }
    if (OUTBF) {
        bf16x8 ov;
        #pragma unroll
        for (int j = 0; j < 8; j++) ov[j] = (__bf16)o[j];
        *(bf16x8*)(outb + row * 512 + lane * 8) = ov;
    } else {
        f32x4 o0 = {o[0], o[1], o[2], o[3]};
        f32x4 o1 = {o[4], o[5], o[6], o[7]};
        *(f32x4*)(outf + row * 512 + lane * 8) = o0;
        *(f32x4*)(outf + row * 512 + lane * 8 + 4) = o1;
    }
}

// ---------------- MFMA GEMM: C[M,N] = A[M,K](bf16) @ BT[N,K](bf16) ----------------
// BM x 128 tile (BM = 128 or 64), BK=32, 3-slot LDS ring with 2-tile-ahead
// prefetch: issue tile s+2, wait vmcnt(2L) -> tiles s+1,s+2 stay in flight
// across the barrier while tile s computes. L = loads/thread/step = BM/64 + 2.
// LDS swizzle: chunk ^= (row>>1)&3 on 64B rows; linear dest + pre-swizzled src.
// 1-D grid, bijective XCD-chunk swizzle, n-fastest for A-panel L2 reuse.
// Epilogue stores are NON-TEMPORAL (outputs are large streams; stop them
// evicting A/B panels from L2 -> cuts FETCH over-read).
// EPI: 1 = qkv -> bf16 out, phi on cols<1024
//      2 = residual add into Cf
//      3 = +bias, gelu, bf16 out
//      4 = +bias, residual add into Cf
template<int EPI, int K, int BM>
__global__ __launch_bounds__(256, 4) void gemm_bt(
    const __bf16* __restrict__ A, const __bf16* __restrict__ BT,
    float* __restrict__ Cf, __bf16* __restrict__ Cb,
    const float* __restrict__ bias, int N, int nbn) {
    constexpr int NT = K / 32;
    constexpr int AL = BM / 64;            // A loads per thread per step
    constexpr int NREP = (BM == 128) ? 4 : 2;
    __shared__ __align__(16) __bf16 Asm[3][BM * 32];
    __shared__ __align__(16) __bf16 Bsm[3][128 * 32];
    const int t = threadIdx.x;
    const int lane = t & 63;
    const int wave = t >> 6;
    const int wr = (BM == 128) ? (wave >> 1) : 0;
    const int wc = (BM == 128) ? (wave & 1) : wave;
    const int nblk = gridDim.x;
    const int q = nblk >> 3, r = nblk & 7;
    const int xcd = blockIdx.x & 7, loc = blockIdx.x >> 3;
    const int swz = (xcd < r ? xcd * (q + 1) : r * (q + 1) + (xcd - r) * q) + loc;
    const int m0 = (swz / nbn) * BM, n0 = (swz % nbn) * 128;
    const int fr = lane & 15, fc = lane >> 4;

    const __bf16* Aps[AL];
    const __bf16* Bps[2];
    int aslot[AL], bslot[2];
    #pragma unroll
    for (int j = 0; j < AL; j++) {
        int slot = t + 256 * j;
        int row = slot >> 2, cp = slot & 3;
        int sc = cp ^ ((row >> 1) & 3);
        Aps[j] = A + (size_t)(m0 + row) * K + sc * 8;
        aslot[j] = slot * 8;
    }
    #pragma unroll
    for (int j = 0; j < 2; j++) {
        int slot = t + 256 * j;
        int row = slot >> 2, cp = slot & 3;
        int sc = cp ^ ((row >> 1) & 3);
        Bps[j] = BT + (size_t)(n0 + row) * K + sc * 8;
        bslot[j] = slot * 8;
    }

    f32x4 acc[4][NREP];
    #pragma unroll
    for (int m = 0; m < 4; m++)
        #pragma unroll
        for (int n = 0; n < NREP; n++)
            acc[m][n] = (f32x4){0.f, 0.f, 0.f, 0.f};

    auto stage = [&](int koff, __bf16* Ad, __bf16* Bd) {
        #pragma unroll
        for (int j = 0; j < AL; j++) GLOAD16(Aps[j] + koff, Ad + aslot[j]);
        #pragma unroll
        for (int j = 0; j < 2; j++) GLOAD16(Bps[j] + koff, Bd + bslot[j]);
    };

    __bf16 *A0 = Asm[0], *A1 = Asm[1], *A2 = Asm[2];
    __bf16 *B0 = Bsm[0], *B1 = Bsm[1], *B2 = Bsm[2];
    stage(0, A0, B0);
    stage(32, A1, B1);

    for (int s = 0; s < NT; s++) {
        if (s + 2 < NT) {
            stage((s + 2) * 32, A2, B2);
            if constexpr (BM == 128) asm volatile("s_waitcnt vmcnt(8)" ::: "memory");
            else                     asm volatile("s_waitcnt vmcnt(6)" ::: "memory");
        } else if (s + 1 < NT) {
            if constexpr (BM == 128) asm volatile("s_waitcnt vmcnt(4)" ::: "memory");
            else                     asm volatile("s_waitcnt vmcnt(3)" ::: "memory");
        } else {
            asm volatile("s_waitcnt vmcnt(0)" ::: "memory");
        }
        __builtin_amdgcn_s_barrier();

        bf16x8 af[4], bfr[NREP];
        #pragma unroll
        for (int m = 0; m < 4; m++) {
            int ra = wr * 64 + m * 16 + fr;
            af[m] = *(const bf16x8*)(A0 + ra * 32 + ((fc ^ ((ra >> 1) & 3)) << 3));
        }
        #pragma unroll
        for (int n = 0; n < NREP; n++) {
            int rb = wc * (16 * NREP) + n * 16 + fr;
            bfr[n] = *(const bf16x8*)(B0 + rb * 32 + ((fc ^ ((rb >> 1) & 3)) << 3));
        }
        __builtin_amdgcn_s_setprio(1);
        #pragma unroll
        for (int m = 0; m < 4; m++)
            #pragma unroll
            for (int n = 0; n < NREP; n++)
                acc[m][n] = __builtin_amdgcn_mfma_f32_16x16x32_bf16(af[m], bfr[n], acc[m][n], 0, 0, 0);
        __builtin_amdgcn_s_setprio(0);
        __builtin_amdgcn_s_barrier();   // readers done before slot reuse

        __bf16* ta = A0; A0 = A1; A1 = A2; A2 = ta;
        __bf16* tb = B0; B0 = B1; B1 = B2; B2 = tb;
    }

    const int cr = (lane >> 4) * 4;
    const int cc = lane & 15;
    #pragma unroll
    for (int m = 0; m < 4; m++) {
        #pragma unroll
        for (int n = 0; n < NREP; n++) {
            #pragma unroll
            for (int r2 = 0; r2 < 4; r2++) {
                int grow = m0 + wr * 64 + m * 16 + cr + r2;
                int gcol = n0 + wc * (16 * NREP) + n * 16 + cc;
                size_t idx = (size_t)grow * N + gcol;
                float val = acc[m][n][r2];
                if (EPI == 1) {
                    if (gcol < 1024) val = fmaxf(val, 0.f) + 1e-3f;
                    nt_store_bf16((__bf16)val, &Cb[idx]);
                } else if (EPI == 2) {
                    __builtin_nontemporal_store(Cf[idx] + val, &Cf[idx]);
                } else if (EPI == 3) {
                    val += bias[gcol];
                    nt_store_bf16((__bf16)gelu_tanh(val), &Cb[idx]);
                } else if (EPI == 4) {
                    __builtin_nontemporal_store(Cf[idx] + val + bias[gcol], &Cf[idx]);
                } else {
                    Cf[idx] = val;
                }
            }
        }
    }
}

// ---------------- kv partial: per (b,h,chunk of 64 rows) 64x64 + pksum ----------------
__global__ __launch_bounds__(256) void kv_partial(const __bf16* __restrict__ qkvb,
                                                  float* __restrict__ part) {
    int bh = blockIdx.x;           // 32
    int chunk = blockIdx.y;        // 64 chunks of 64 rows
    int b = bh >> 3, hh = bh & 7;
    int t = threadIdx.x;
    int f = t & 63, eg = t >> 6;   // e-base = eg*16
    size_t base = ((size_t)b * SEQ + (size_t)chunk * 64) * 1536;
    const __bf16* kcol = qkvb + base + 512 + hh * 64 + f;
    const __bf16* vrow = qkvb + base + 1024 + hh * 64 + eg * 16;
    float psum = 0.f;
    f32x4 a0 = {0.f,0.f,0.f,0.f}, a1 = a0, a2 = a0, a3 = a0;
    for (int s = 0; s < 64; s++) {
        size_t o = (size_t)s * 1536;
        float pk = (float)kcol[o];
        psum += pk;
        bf16x8 w0 = *(const bf16x8*)(vrow + o);
        bf16x8 w1 = *(const bf16x8*)(vrow + o + 8);
        #pragma unroll
        for (int j = 0; j < 4; j++) {
            a0[j] += (float)w0[j]     * pk;
            a1[j] += (float)w0[4 + j] * pk;
            a2[j] += (float)w1[j]     * pk;
            a3[j] += (float)w1[4 + j] * pk;
        }
    }
    float* dst = part + ((size_t)chunk * 32 + bh) * 4160 + (size_t)f * 65 + eg * 16;
    #pragma unroll
    for (int j = 0; j < 4; j++) { dst[j] = a0[j]; dst[4+j] = a1[j]; dst[8+j] = a2[j]; dst[12+j] = a3[j]; }
    if (eg == 0) dst[64] = psum;   // pksum slot
}

__global__ void kv_reduce(const float* __restrict__ part, float* __restrict__ kvfin) {
    int i = blockIdx.x * 256 + threadIdx.x;
    if (i >= 32 * 4160) return;
    float s = 0.f;
    #pragma unroll 8
    for (int c = 0; c < 64; c++) s += part[(size_t)c * (32 * 4160) + i];
    kvfin[i] = s;
}

// ---------------- num / den / divide -> attn (bf16), MFMA version ----------------
// Per block: (b,h) x 128-row chunk. PQ(128x64) @ KV(64x64) via 16 MFMA/wave,
// KV staged once as bf16 in LDS ([64][68] pad -> 2-way conflict = free),
// den computed by a 2-thread-per-row cooperative dot with ps.
__global__ __launch_bounds__(256) void num_attn(const __bf16* __restrict__ qkvb,
                                                const float* __restrict__ kvfin,
                                                __bf16* __restrict__ attn) {
    __shared__ __bf16 kvb[64][68];
    __shared__ float ps[64];
    __shared__ float dens[128];
    int bh = blockIdx.x, chunk = blockIdx.y;   // 32 x 32
    int b = bh >> 3, hh = bh & 7;
    const float* src = kvfin + (size_t)bh * 4160;
    int t = threadIdx.x;
    for (int i = t; i < 4096; i += 256) {
        int f = i >> 6, e = i & 63;
        kvb[f][e] = (__bf16)src[f * 65 + e];
    }
    if (t < 64) ps[t] = src[t * 65 + 64];
    __syncthreads();
    // den per row (2 threads per row)
    {
        int rr = t >> 1, hf = t & 1;
        size_t grow = (size_t)b * SEQ + (size_t)chunk * 128 + rr;
        const __bf16* pqr = qkvb + grow * 1536 + hh * 64 + hf * 32;
        float d = 0.f;
        #pragma unroll
        for (int j = 0; j < 4; j++) {
            bf16x8 v = *(const bf16x8*)(pqr + 8 * j);
            #pragma unroll
            for (int k = 0; k < 8; k++) d += (float)v[k] * ps[hf * 32 + 8 * j + k];
        }
        d += __shfl_xor(d, 1);
        if (hf == 0) dens[rr] = d;
    }
    // MFMA: wave w owns rows w*32 .. w*32+31
    const int lane = t & 63, w = t >> 6;
    const int fr = lane & 15, fc = lane >> 4;
    size_t rowbase = (size_t)b * SEQ + (size_t)chunk * 128 + w * 32;
    bf16x8 a[2][2];
    #pragma unroll
    for (int rt = 0; rt < 2; rt++)
        #pragma unroll
        for (int ks = 0; ks < 2; ks++)
            a[rt][ks] = *(const bf16x8*)(qkvb + (rowbase + rt * 16 + fr) * 1536 + hh * 64 + ks * 32 + fc * 8);
    __syncthreads();   // dens + kvb visible to all
    bf16x8 bfrag[4][2];
    #pragma unroll
    for (int n = 0; n < 4; n++)
        #pragma unroll
        for (int ks = 0; ks < 2; ks++) {
            bf16x8 bv;
            #pragma unroll
            for (int j = 0; j < 8; j++) bv[j] = kvb[ks * 32 + fc * 8 + j][n * 16 + fr];
            bfrag[n][ks] = bv;
        }
    f32x4 acc[2][4];
    #pragma unroll
    for (int rt = 0; rt < 2; rt++)
        #pragma unroll
        for (int n = 0; n < 4; n++)
            acc[rt][n] = (f32x4){0.f, 0.f, 0.f, 0.f};
    #pragma unroll
    for (int ks = 0; ks < 2; ks++)
        #pragma unroll
        for (int rt = 0; rt < 2; rt++)
            #pragma unroll
            for (int n = 0; n < 4; n++)
                acc[rt][n] = __builtin_amdgcn_mfma_f32_16x16x32_bf16(a[rt][ks], bfrag[n][ks], acc[rt][n], 0, 0, 0);
    const int cr = (lane >> 4) * 4, cc = lane & 15;
    #pragma unroll
    for (int rt = 0; rt < 2; rt++) {
        #pragma unroll
        for (int r2 = 0; r2 < 4; r2++) {
            int lr = w * 32 + rt * 16 + cr + r2;
            float rd = 1.f / dens[lr];
            size_t grow = (size_t)b * SEQ + (size_t)chunk * 128 + lr;
            #pragma unroll
            for (int n = 0; n < 4; n++)
                attn[grow * 512 + hh * 64 + n * 16 + cc] = (__bf16)(acc[rt][n][r2] * rd);
        }
    }
}

extern "C" void kernel_launch(void* const* d_in, const int* in_sizes, int n_in,
                              void* d_out, int out_size, void* d_ws, size_t ws_size,
                              hipStream_t stream) {
    const int*   tokens = (const int*)d_in[0];
    const float* embed  = (const float*)d_in[1];
    const float* Wq     = (const float*)d_in[2];
    const float* Wk     = (const float*)d_in[3];
    const float* Wv     = (const float*)d_in[4];
    const float* Wo     = (const float*)d_in[5];
    const float* ln1_s  = (const float*)d_in[6];
    const float* ln1_b  = (const float*)d_in[7];
    const float* W1     = (const float*)d_in[8];
    const float* b1     = (const float*)d_in[9];
    const float* W2     = (const float*)d_in[10];
    const float* b2     = (const float*)d_in[11];
    const float* ln2_s  = (const float*)d_in[12];
    const float* ln2_b  = (const float*)d_in[13];
    const float* lnf_s  = (const float*)d_in[14];
    const float* lnf_b  = (const float*)d_in[15];
    float* out = (float*)d_out;

    float* ws = (float*)d_ws;
    size_t off = 0;
    float* pos = ws;               off += 2097152;            // 4096*512 f32
    float* x   = ws + off;         off += 8388608;            // 16384*512 f32
    __bf16* h    = (__bf16*)(ws + off); off += 4194304;       // 16384*512 bf16
    __bf16* attn = (__bf16*)(ws + off); off += 4194304;       // 16384*512 bf16
    __bf16* qkvb = (__bf16*)(ws + off);                       // 16384*1536 bf16
    __bf16* hid  = (__bf16*)(ws + off); off += 16777216;      // 16384*2048 bf16 (union, serialized)
    float* kvpart = ws + off;      off += 64 * 32 * 4160;     // partials (64 chunks)
    float* kvfin  = ws + off;      off += 32 * 4160;
    __bf16* wbuf  = (__bf16*)(ws + off);                      // 6 * 3145728 bf16

    pos_kernel<<<4096, 256, 0, stream>>>(pos);
    transpose_bf16<<<dim3(16, 16, 6), dim3(32, 8), 0, stream>>>(Wq, wbuf,          512, 512,  262144, 3145728);
    transpose_bf16<<<dim3(16, 16, 6), dim3(32, 8), 0, stream>>>(Wk, wbuf + 262144, 512, 512,  262144, 3145728);
    transpose_bf16<<<dim3(16, 16, 6), dim3(32, 8), 0, stream>>>(Wv, wbuf + 524288, 512, 512,  262144, 3145728);
    transpose_bf16<<<dim3(16, 16, 6), dim3(32, 8), 0, stream>>>(Wo, wbuf + 786432, 512, 512,  262144, 3145728);
    transpose_bf16<<<dim3(64, 16, 6), dim3(32, 8), 0, stream>>>(W1, wbuf + 1048576, 512, 2048, 1048576, 3145728);
    transpose_bf16<<<dim3(16, 64, 6), dim3(32, 8), 0, stream>>>(W2, wbuf + 2097152, 2048, 512, 1048576, 3145728);
    embed_kernel<<<16384, 128, 0, stream>>>(tokens, embed, pos, x);

    for (int l = 0; l < 6; l++) {
        const __bf16* wl = wbuf + (size_t)l * 3145728;
        ln_kernel<1><<<4096, 256, 0, stream>>>(x, ln1_s + l * 512, ln1_b + l * 512, h, nullptr);
        gemm_bt<1, 512, 128><<<1536, 256, 0, stream>>>(h, wl, nullptr, qkvb, nullptr, 1536, 12);
        kv_partial<<<dim3(32, 64), 256, 0, stream>>>(qkvb, kvpart);
        kv_reduce<<<520, 256, 0, stream>>>(kvpart, kvfin);
        num_attn<<<dim3(32, 32), 256, 0, stream>>>(qkvb, kvfin, attn);
        gemm_bt<2, 512, 64><<<1024, 256, 0, stream>>>(attn, wl + 786432, x, nullptr, nullptr, 512, 4);
        ln_kernel<1><<<4096, 256, 0, stream>>>(x, ln2_s + l * 512, ln2_b + l * 512, h, nullptr);
        gemm_bt<3, 512, 128><<<2048, 256, 0, stream>>>(h, wl + 1048576, nullptr, hid, b1 + (size_t)l * 2048, 2048, 16);
        gemm_bt<4, 2048, 64><<<1024, 256, 0, stream>>>(hid, wl + 2097152, x, nullptr, b2 + (size_t)l * 512, 512, 4);
    }
    ln_kernel<0><<<4096, 256, 0, stream>>>(x, lnf_s, lnf_b, nullptr, out);
}

// Round 9
// 1744.770 us; speedup vs baseline: 1.1335x; 1.1335x over previous
//
#include <hip/hip_runtime.h>

typedef float f32x4 __attribute__((ext_vector_type(4)));
typedef __bf16 bf16x8 __attribute__((ext_vector_type(8)));

#define NROWS 16384   // B*S
#define SEQ   4096
#define EMBD  512
#define MLPD  2048

__device__ inline float gelu_tanh(float x) {
    float t = 0.7978845608028654f * (x + 0.044715f * x * x * x);
    float e = __expf(2.f * t);
    float th = 1.f - 2.f / (1.f + e);
    return 0.5f * x * (1.f + th);
}

// direct global->LDS 16B DMA; LDS dest must be linear in lane order
#define GLOAD16(gp, lp)                                                        \
    __builtin_amdgcn_global_load_lds(                                          \
        (const __attribute__((address_space(1))) void*)(gp),                   \
        (__attribute__((address_space(3))) void*)(lp), 16, 0, 0)

// ---------------- positional table: pos[s][512] ----------------
__global__ void pos_kernel(float* __restrict__ pos) {
    int i = blockIdx.x * 256 + threadIdx.x;        // 4096*256
    int s = i >> 8, j = i & 255;
    float div = __expf((float)j * (-2.f * 9.210340371976184f / 512.f));
    float a = (float)s * div;
    pos[(size_t)s * 512 + 2 * j]     = sinf(a);
    pos[(size_t)s * 512 + 2 * j + 1] = cosf(a);
}

// ---------------- embedding gather + pos add ----------------
__global__ void embed_kernel(const int* __restrict__ tokens,
                             const float* __restrict__ embed,
                             const float* __restrict__ pos,
                             float* __restrict__ x) {
    int row = blockIdx.x;            // 16384
    int t = threadIdx.x;             // 128
    int s = row & (SEQ - 1);
    int tok = tokens[row];
    f32x4 e = *(const f32x4*)(embed + (size_t)tok * 512 + t * 4);
    f32x4 p = *(const f32x4*)(pos + (size_t)s * 512 + t * 4);
    e += p;
    *(f32x4*)(x + (size_t)row * 512 + t * 4) = e;
}

// ---------------- transpose fp32 [K][N] -> bf16 [N][K], batched over z ----------------
__global__ void transpose_bf16(const float* __restrict__ in, __bf16* __restrict__ out,
                               int K, int N, size_t in_lstride, size_t out_lstride) {
    __shared__ float tile[32][33];
    in  += (size_t)blockIdx.z * in_lstride;
    out += (size_t)blockIdx.z * out_lstride;
    int n0 = blockIdx.x * 32, k0 = blockIdx.y * 32;
    int tx = threadIdx.x, ty = threadIdx.y;   // 32 x 8
    #pragma unroll
    for (int i = 0; i < 32; i += 8)
        tile[ty + i][tx] = in[(size_t)(k0 + ty + i) * N + n0 + tx];
    __syncthreads();
    #pragma unroll
    for (int i = 0; i < 32; i += 8)
        out[(size_t)(n0 + ty + i) * K + k0 + tx] = (__bf16)tile[tx][ty + i];
}

// ---------------- LayerNorm (one wave per 512-row) ----------------
template<int OUTBF>
__global__ __launch_bounds__(256) void ln_kernel(
    const float* __restrict__ x, const float* __restrict__ gamma,
    const float* __restrict__ beta, __bf16* __restrict__ outb,
    float* __restrict__ outf) {
    int lane = threadIdx.x & 63;
    size_t row = (size_t)blockIdx.x * 4 + (threadIdx.x >> 6);
    const float* xr = x + row * 512 + lane * 8;
    f32x4 v0 = *(const f32x4*)xr;
    f32x4 v1 = *(const f32x4*)(xr + 4);
    float sum = (v0[0] + v0[1]) + (v0[2] + v0[3]) + (v1[0] + v1[1]) + (v1[2] + v1[3]);
    #pragma unroll
    for (int off = 32; off; off >>= 1) sum += __shfl_xor(sum, off);
    float mu = sum * (1.f / 512.f);
    float vs = 0.f;
    #pragma unroll
    for (int j = 0; j < 4; j++) {
        float d0 = v0[j] - mu; vs += d0 * d0;
        float d1 = v1[j] - mu; vs += d1 * d1;
    }
    #pragma unroll
    for (int off = 32; off; off >>= 1) vs += __shfl_xor(vs, off);
    float inv = rsqrtf(vs * (1.f / 512.f) + 1e-6f);
    const float* gp = gamma + lane * 8;
    const float* bp = beta + lane * 8;
    f32x4 g0 = *(const f32x4*)gp, g1 = *(const f32x4*)(gp + 4);
    f32x4 bb0 = *(const f32x4*)bp, bb1 = *(const f32x4*)(bp + 4);
    float o[8];
    #pragma unroll
    for (int j = 0; j < 4; j++) {
        o[j]     = (v0[j] - mu) * inv * g0[j] + bb0[j];
        o[4 + j] = (v1[j] - mu) * inv * g1[j] + bb1[j];
    }
    if (OUTBF) {
        bf16x8 ov;
        #pragma unroll
        for (int j = 0; j < 8; j++) ov[j] = (__bf16)o[j];
        *(bf16x8*)(outb + row * 512 + lane * 8) = ov;
    } else {
        f32x4 o0 = {o[0], o[1], o[2], o[3]};
        f32x4 o1 = {o[4], o[5], o[6], o[7]};
        *(f32x4*)(outf + row * 512 + lane * 8) = o0;
        *(f32x4*)(outf + row * 512 + lane * 8 + 4) = o1;
    }
}

// ---------------- MFMA GEMM: C[M,N] = A[M,K](bf16) @ BT[N,K](bf16) ----------------
// R5-best structure: BM x 128 tile, BK=32, 2-slot double-buffered LDS,
// counted vmcnt(L): next K-tile's L global_load_lds stay in flight across the
// barrier while current tile computes. L = loads/thread/step = BM/64 + 2.
// LDS swizzle: chunk ^= (row>>1)&3 on 64B rows; linear dest + pre-swizzled src.
// Grid: 1-D, bijective XCD-chunk swizzle, M-FASTEST within a chunk:
// consecutive blocks share the (small, L2-resident) B-panel and read disjoint
// A rows -> A fetched exactly once, no reliance on co-residency timing.
// EPI: 1 = qkv -> bf16 out, phi on cols<1024
//      2 = residual add into Cf
//      3 = +bias, gelu, bf16 out
//      4 = +bias, residual add into Cf
template<int EPI, int K, int BM>
__global__ __launch_bounds__(256, 4) void gemm_bt(
    const __bf16* __restrict__ A, const __bf16* __restrict__ BT,
    float* __restrict__ Cf, __bf16* __restrict__ Cb,
    const float* __restrict__ bias, int N, int nbm) {
    constexpr int NT = K / 32;
    constexpr int AL = BM / 64;            // A loads per thread per step
    constexpr int LPS = AL + 2;            // total loads per thread per step
    constexpr int NREP = (BM == 128) ? 4 : 2;
    __shared__ __align__(16) __bf16 Abuf[2][BM * 32];
    __shared__ __align__(16) __bf16 Bbuf[2][128 * 32];
    const int t = threadIdx.x;
    const int lane = t & 63;
    const int wave = t >> 6;
    const int wr = (BM == 128) ? (wave >> 1) : 0;
    const int wc = (BM == 128) ? (wave & 1) : wave;
    const int nblk = gridDim.x;
    const int q = nblk >> 3, r = nblk & 7;
    const int xcd = blockIdx.x & 7, loc = blockIdx.x >> 3;
    const int swz = (xcd < r ? xcd * (q + 1) : r * (q + 1) + (xcd - r) * q) + loc;
    const int m0 = (swz % nbm) * BM, n0 = (swz / nbm) * 128;   // m-fastest
    const int fr = lane & 15, fc = lane >> 4;

    const __bf16* Aps[AL];
    const __bf16* Bps[2];
    int aslot[AL], bslot[2];
    #pragma unroll
    for (int j = 0; j < AL; j++) {
        int slot = t + 256 * j;
        int row = slot >> 2, cp = slot & 3;
        int sc = cp ^ ((row >> 1) & 3);
        Aps[j] = A + (size_t)(m0 + row) * K + sc * 8;
        aslot[j] = slot * 8;
    }
    #pragma unroll
    for (int j = 0; j < 2; j++) {
        int slot = t + 256 * j;
        int row = slot >> 2, cp = slot & 3;
        int sc = cp ^ ((row >> 1) & 3);
        Bps[j] = BT + (size_t)(n0 + row) * K + sc * 8;
        bslot[j] = slot * 8;
    }

    f32x4 acc[4][NREP];
    #pragma unroll
    for (int m = 0; m < 4; m++)
        #pragma unroll
        for (int n = 0; n < NREP; n++)
            acc[m][n] = (f32x4){0.f, 0.f, 0.f, 0.f};

    auto stage = [&](int koff, __bf16* Ad, __bf16* Bd) {
        #pragma unroll
        for (int j = 0; j < AL; j++) GLOAD16(Aps[j] + koff, Ad + aslot[j]);
        #pragma unroll
        for (int j = 0; j < 2; j++) GLOAD16(Bps[j] + koff, Bd + bslot[j]);
    };

    int cur = 0;
    stage(0, Abuf[0], Bbuf[0]);

    for (int s = 0; s < NT; s++) {
        __bf16* Ac = Abuf[cur];     __bf16* Bc = Bbuf[cur];
        if (s + 1 < NT) {
            stage((s + 1) * 32, Abuf[cur ^ 1], Bbuf[cur ^ 1]);
            asm volatile("s_waitcnt vmcnt(%0)" :: "i"(LPS) : "memory");  // cur landed; next in flight
        } else {
            asm volatile("s_waitcnt vmcnt(0)" ::: "memory");
        }
        __builtin_amdgcn_s_barrier();

        bf16x8 af[4], bfr[NREP];
        #pragma unroll
        for (int m = 0; m < 4; m++) {
            int ra = ((BM == 128) ? wr * 64 : 0) + m * 16 + fr;
            af[m] = *(const bf16x8*)(Ac + ra * 32 + ((fc ^ ((ra >> 1) & 3)) << 3));
        }
        #pragma unroll
        for (int n = 0; n < NREP; n++) {
            int rb = wc * (16 * NREP) + n * 16 + fr;
            bfr[n] = *(const bf16x8*)(Bc + rb * 32 + ((fc ^ ((rb >> 1) & 3)) << 3));
        }
        __builtin_amdgcn_s_setprio(1);
        #pragma unroll
        for (int m = 0; m < 4; m++)
            #pragma unroll
            for (int n = 0; n < NREP; n++)
                acc[m][n] = __builtin_amdgcn_mfma_f32_16x16x32_bf16(af[m], bfr[n], acc[m][n], 0, 0, 0);
        __builtin_amdgcn_s_setprio(0);
        __builtin_amdgcn_s_barrier();   // readers done before overwrite of this buffer
        cur ^= 1;
    }

    const int cr = (lane >> 4) * 4;
    const int cc = lane & 15;
    #pragma unroll
    for (int m = 0; m < 4; m++) {
        #pragma unroll
        for (int n = 0; n < NREP; n++) {
            #pragma unroll
            for (int r2 = 0; r2 < 4; r2++) {
                int grow = m0 + ((BM == 128) ? wr * 64 : 0) + m * 16 + cr + r2;
                int gcol = n0 + wc * (16 * NREP) + n * 16 + cc;
                size_t idx = (size_t)grow * N + gcol;
                float val = acc[m][n][r2];
                if (EPI == 1) {
                    if (gcol < 1024) val = fmaxf(val, 0.f) + 1e-3f;
                    Cb[idx] = (__bf16)val;
                } else if (EPI == 2) {
                    Cf[idx] += val;
                } else if (EPI == 3) {
                    val += bias[gcol];
                    Cb[idx] = (__bf16)gelu_tanh(val);
                } else if (EPI == 4) {
                    Cf[idx] += val + bias[gcol];
                } else {
                    Cf[idx] = val;
                }
            }
        }
    }
}

// ---------------- kv partial: per (b,h,chunk of 64 rows) 64x64 + pksum ----------------
__global__ __launch_bounds__(256) void kv_partial(const __bf16* __restrict__ qkvb,
                                                  float* __restrict__ part) {
    int bh = blockIdx.x;           // 32
    int chunk = blockIdx.y;        // 64 chunks of 64 rows
    int b = bh >> 3, hh = bh & 7;
    int t = threadIdx.x;
    int f = t & 63, eg = t >> 6;   // e-base = eg*16
    size_t base = ((size_t)b * SEQ + (size_t)chunk * 64) * 1536;
    const __bf16* kcol = qkvb + base + 512 + hh * 64 + f;
    const __bf16* vrow = qkvb + base + 1024 + hh * 64 + eg * 16;
    float psum = 0.f;
    f32x4 a0 = {0.f,0.f,0.f,0.f}, a1 = a0, a2 = a0, a3 = a0;
    for (int s = 0; s < 64; s++) {
        size_t o = (size_t)s * 1536;
        float pk = (float)kcol[o];
        psum += pk;
        bf16x8 w0 = *(const bf16x8*)(vrow + o);
        bf16x8 w1 = *(const bf16x8*)(vrow + o + 8);
        #pragma unroll
        for (int j = 0; j < 4; j++) {
            a0[j] += (float)w0[j]     * pk;
            a1[j] += (float)w0[4 + j] * pk;
            a2[j] += (float)w1[j]     * pk;
            a3[j] += (float)w1[4 + j] * pk;
        }
    }
    float* dst = part + ((size_t)chunk * 32 + bh) * 4160 + (size_t)f * 65 + eg * 16;
    #pragma unroll
    for (int j = 0; j < 4; j++) { dst[j] = a0[j]; dst[4+j] = a1[j]; dst[8+j] = a2[j]; dst[12+j] = a3[j]; }
    if (eg == 0) dst[64] = psum;   // pksum slot
}

__global__ void kv_reduce(const float* __restrict__ part, float* __restrict__ kvfin) {
    int i = blockIdx.x * 256 + threadIdx.x;
    if (i >= 32 * 4160) return;
    float s = 0.f;
    #pragma unroll 8
    for (int c = 0; c < 64; c++) s += part[(size_t)c * (32 * 4160) + i];
    kvfin[i] = s;
}

// ---------------- num / den / divide -> attn (bf16), MFMA with den column ----
// Per block: (b,h) x 128-row chunk. PQ(128x64) @ [KV | ps | 0](64x80):
// n-tiles 0..3 = numerator cols, n-tile 4 col 64 = ps -> acc[.][4] IS den.
// den broadcast within wave via __shfl from lanes cc==0 (C layout: col 64).
// kvb stride 86 elems: fc row-steps land on distinct bank groups.
__global__ __launch_bounds__(256) void num_attn(const __bf16* __restrict__ qkvb,
                                                const float* __restrict__ kvfin,
                                                __bf16* __restrict__ attn) {
    __shared__ __bf16 kvb[64][86];
    int bh = blockIdx.x, chunk = blockIdx.y;   // 32 x 32
    int b = bh >> 3, hh = bh & 7;
    const float* src = kvfin + (size_t)bh * 4160;
    int t = threadIdx.x;
    for (int i = t; i < 4096; i += 256) {
        int f = i >> 6, e = i & 63;
        kvb[f][e] = (__bf16)src[f * 65 + e];
    }
    if (t < 64) {
        kvb[t][64] = (__bf16)src[t * 65 + 64];     // ps column
        #pragma unroll
        for (int e = 65; e < 80; e++) kvb[t][e] = (__bf16)0.f;
    }
    const int lane = t & 63, w = t >> 6;
    const int fr = lane & 15, fc = lane >> 4;
    size_t rowbase = (size_t)b * SEQ + (size_t)chunk * 128 + w * 32;
    bf16x8 a[2][2];
    #pragma unroll
    for (int rt = 0; rt < 2; rt++)
        #pragma unroll
        for (int ks = 0; ks < 2; ks++)
            a[rt][ks] = *(const bf16x8*)(qkvb + (rowbase + rt * 16 + fr) * 1536 + hh * 64 + ks * 32 + fc * 8);
    __syncthreads();   // kvb visible
    bf16x8 bfrag[5][2];
    #pragma unroll
    for (int n = 0; n < 5; n++)
        #pragma unroll
        for (int ks = 0; ks < 2; ks++) {
            bf16x8 bv;
            #pragma unroll
            for (int j = 0; j < 8; j++) bv[j] = kvb[ks * 32 + fc * 8 + j][n * 16 + fr];
            bfrag[n][ks] = bv;
        }
    f32x4 acc[2][5];
    #pragma unroll
    for (int rt = 0; rt < 2; rt++)
        #pragma unroll
        for (int n = 0; n < 5; n++)
            acc[rt][n] = (f32x4){0.f, 0.f, 0.f, 0.f};
    #pragma unroll
    for (int ks = 0; ks < 2; ks++)
        #pragma unroll
        for (int rt = 0; rt < 2; rt++)
            #pragma unroll
            for (int n = 0; n < 5; n++)
                acc[rt][n] = __builtin_amdgcn_mfma_f32_16x16x32_bf16(a[rt][ks], bfrag[n][ks], acc[rt][n], 0, 0, 0);
    const int cr = (lane >> 4) * 4, cc = lane & 15;
    #pragma unroll
    for (int rt = 0; rt < 2; rt++) {
        float rdv[4];
        #pragma unroll
        for (int r2 = 0; r2 < 4; r2++)
            rdv[r2] = 1.f / __shfl(acc[rt][4][r2], lane & 48);   // den from cc==0 lane, same rows
        #pragma unroll
        for (int r2 = 0; r2 < 4; r2++) {
            int lr = w * 32 + rt * 16 + cr + r2;
            size_t grow = (size_t)b * SEQ + (size_t)chunk * 128 + lr;
            #pragma unroll
            for (int n = 0; n < 4; n++)
                attn[grow * 512 + hh * 64 + n * 16 + cc] = (__bf16)(acc[rt][n][r2] * rdv[r2]);
        }
    }
}

extern "C" void kernel_launch(void* const* d_in, const int* in_sizes, int n_in,
                              void* d_out, int out_size, void* d_ws, size_t ws_size,
                              hipStream_t stream) {
    const int*   tokens = (const int*)d_in[0];
    const float* embed  = (const float*)d_in[1];
    const float* Wq     = (const float*)d_in[2];
    const float* Wk     = (const float*)d_in[3];
    const float* Wv     = (const float*)d_in[4];
    const float* Wo     = (const float*)d_in[5];
    const float* ln1_s  = (const float*)d_in[6];
    const float* ln1_b  = (const float*)d_in[7];
    const float* W1     = (const float*)d_in[8];
    const float* b1     = (const float*)d_in[9];
    const float* W2     = (const float*)d_in[10];
    const float* b2     = (const float*)d_in[11];
    const float* ln2_s  = (const float*)d_in[12];
    const float* ln2_b  = (const float*)d_in[13];
    const float* lnf_s  = (const float*)d_in[14];
    const float* lnf_b  = (const float*)d_in[15];
    float* out = (float*)d_out;

    float* ws = (float*)d_ws;
    size_t off = 0;
    float* pos = ws;               off += 2097152;            // 4096*512 f32
    float* x   = ws + off;         off += 8388608;            // 16384*512 f32
    __bf16* h    = (__bf16*)(ws + off); off += 4194304;       // 16384*512 bf16
    __bf16* attn = (__bf16*)(ws + off); off += 4194304;       // 16384*512 bf16
    __bf16* qkvb = (__bf16*)(ws + off);                       // 16384*1536 bf16
    __bf16* hid  = (__bf16*)(ws + off); off += 16777216;      // 16384*2048 bf16 (union, serialized)
    float* kvpart = ws + off;      off += 64 * 32 * 4160;     // partials (64 chunks)
    float* kvfin  = ws + off;      off += 32 * 4160;
    __bf16* wbuf  = (__bf16*)(ws + off);                      // 6 * 3145728 bf16

    pos_kernel<<<4096, 256, 0, stream>>>(pos);
    transpose_bf16<<<dim3(16, 16, 6), dim3(32, 8), 0, stream>>>(Wq, wbuf,          512, 512,  262144, 3145728);
    transpose_bf16<<<dim3(16, 16, 6), dim3(32, 8), 0, stream>>>(Wk, wbuf + 262144, 512, 512,  262144, 3145728);
    transpose_bf16<<<dim3(16, 16, 6), dim3(32, 8), 0, stream>>>(Wv, wbuf + 524288, 512, 512,  262144, 3145728);
    transpose_bf16<<<dim3(16, 16, 6), dim3(32, 8), 0, stream>>>(Wo, wbuf + 786432, 512, 512,  262144, 3145728);
    transpose_bf16<<<dim3(64, 16, 6), dim3(32, 8), 0, stream>>>(W1, wbuf + 1048576, 512, 2048, 1048576, 3145728);
    transpose_bf16<<<dim3(16, 64, 6), dim3(32, 8), 0, stream>>>(W2, wbuf + 2097152, 2048, 512, 1048576, 3145728);
    embed_kernel<<<16384, 128, 0, stream>>>(tokens, embed, pos, x);

    for (int l = 0; l < 6; l++) {
        const __bf16* wl = wbuf + (size_t)l * 3145728;
        ln_kernel<1><<<4096, 256, 0, stream>>>(x, ln1_s + l * 512, ln1_b + l * 512, h, nullptr);
        gemm_bt<1, 512, 128><<<1536, 256, 0, stream>>>(h, wl, nullptr, qkvb, nullptr, 1536, 128);
        kv_partial<<<dim3(32, 64), 256, 0, stream>>>(qkvb, kvpart);
        kv_reduce<<<520, 256, 0, stream>>>(kvpart, kvfin);
        num_attn<<<dim3(32, 32), 256, 0, stream>>>(qkvb, kvfin, attn);
        gemm_bt<2, 512, 64><<<1024, 256, 0, stream>>>(attn, wl + 786432, x, nullptr, nullptr, 512, 256);
        ln_kernel<1><<<4096, 256, 0, stream>>>(x, ln2_s + l * 512, ln2_b + l * 512, h, nullptr);
        gemm_bt<3, 512, 128><<<2048, 256, 0, stream>>>(h, wl + 1048576, nullptr, hid, b1 + (size_t)l * 2048, 2048, 128);
        gemm_bt<4, 2048, 64><<<1024, 256, 0, stream>>>(hid, wl + 2097152, x, nullptr, b2 + (size_t)l * 512, 512, 256);
    }
    ln_kernel<0><<<4096, 256, 0, stream>>>(x, lnf_s, lnf_b, nullptr, out);
}

// Round 10
// 1743.791 us; speedup vs baseline: 1.1342x; 1.0006x over previous
//
#include <hip/hip_runtime.h>

typedef float f32x4 __attribute__((ext_vector_type(4)));
typedef __bf16 bf16x8 __attribute__((ext_vector_type(8)));

#define NROWS 16384   // B*S
#define SEQ   4096
#define EMBD  512
#define MLPD  2048

__device__ inline float gelu_tanh(float x) {
    float t = 0.7978845608028654f * (x + 0.044715f * x * x * x);
    float e = __expf(2.f * t);
    float th = 1.f - 2.f / (1.f + e);
    return 0.5f * x * (1.f + th);
}

// direct global->LDS 16B DMA; LDS dest must be linear in lane order
#define GLOAD16(gp, lp)                                                        \
    __builtin_amdgcn_global_load_lds(                                          \
        (const __attribute__((address_space(1))) void*)(gp),                   \
        (__attribute__((address_space(3))) void*)(lp), 16, 0, 0)

// ---------------- positional table: pos[s][512] ----------------
__global__ void pos_kernel(float* __restrict__ pos) {
    int i = blockIdx.x * 256 + threadIdx.x;        // 4096*256
    int s = i >> 8, j = i & 255;
    float div = __expf((float)j * (-2.f * 9.210340371976184f / 512.f));
    float a = (float)s * div;
    pos[(size_t)s * 512 + 2 * j]     = sinf(a);
    pos[(size_t)s * 512 + 2 * j + 1] = cosf(a);
}

// ---------------- embedding gather + pos add ----------------
__global__ void embed_kernel(const int* __restrict__ tokens,
                             const float* __restrict__ embed,
                             const float* __restrict__ pos,
                             float* __restrict__ x) {
    int row = blockIdx.x;            // 16384
    int t = threadIdx.x;             // 128
    int s = row & (SEQ - 1);
    int tok = tokens[row];
    f32x4 e = *(const f32x4*)(embed + (size_t)tok * 512 + t * 4);
    f32x4 p = *(const f32x4*)(pos + (size_t)s * 512 + t * 4);
    e += p;
    *(f32x4*)(x + (size_t)row * 512 + t * 4) = e;
}

// ---------------- transpose fp32 [K][N] -> bf16 [N][K], batched over z ----------------
__global__ void transpose_bf16(const float* __restrict__ in, __bf16* __restrict__ out,
                               int K, int N, size_t in_lstride, size_t out_lstride) {
    __shared__ float tile[32][33];
    in  += (size_t)blockIdx.z * in_lstride;
    out += (size_t)blockIdx.z * out_lstride;
    int n0 = blockIdx.x * 32, k0 = blockIdx.y * 32;
    int tx = threadIdx.x, ty = threadIdx.y;   // 32 x 8
    #pragma unroll
    for (int i = 0; i < 32; i += 8)
        tile[ty + i][tx] = in[(size_t)(k0 + ty + i) * N + n0 + tx];
    __syncthreads();
    #pragma unroll
    for (int i = 0; i < 32; i += 8)
        out[(size_t)(n0 + ty + i) * K + k0 + tx] = (__bf16)tile[tx][ty + i];
}

// ---------------- LayerNorm (one wave per 512-row) ----------------
template<int OUTBF>
__global__ __launch_bounds__(256) void ln_kernel(
    const float* __restrict__ x, const float* __restrict__ gamma,
    const float* __restrict__ beta, __bf16* __restrict__ outb,
    float* __restrict__ outf) {
    int lane = threadIdx.x & 63;
    size_t row = (size_t)blockIdx.x * 4 + (threadIdx.x >> 6);
    const float* xr = x + row * 512 + lane * 8;
    f32x4 v0 = *(const f32x4*)xr;
    f32x4 v1 = *(const f32x4*)(xr + 4);
    float sum = (v0[0] + v0[1]) + (v0[2] + v0[3]) + (v1[0] + v1[1]) + (v1[2] + v1[3]);
    #pragma unroll
    for (int off = 32; off; off >>= 1) sum += __shfl_xor(sum, off);
    float mu = sum * (1.f / 512.f);
    float vs = 0.f;
    #pragma unroll
    for (int j = 0; j < 4; j++) {
        float d0 = v0[j] - mu; vs += d0 * d0;
        float d1 = v1[j] - mu; vs += d1 * d1;
    }
    #pragma unroll
    for (int off = 32; off; off >>= 1) vs += __shfl_xor(vs, off);
    float inv = rsqrtf(vs * (1.f / 512.f) + 1e-6f);
    const float* gp = gamma + lane * 8;
    const float* bp = beta + lane * 8;
    f32x4 g0 = *(const f32x4*)gp, g1 = *(const f32x4*)(gp + 4);
    f32x4 bb0 = *(const f32x4*)bp, bb1 = *(const f32x4*)(bp + 4);
    float o[8];
    #pragma unroll
    for (int j = 0; j < 4; j++) {
        o[j]     = (v0[j] - mu) * inv * g0[j] + bb0[j];
        o[4 + j] = (v1[j] - mu) * inv * g1[j] + bb1[j];
    }
    if (OUTBF) {
        bf16x8 ov;
        #pragma unroll
        for (int j = 0; j < 8; j++) ov[j] = (__bf16)o[j];
        *(bf16x8*)(outb + row * 512 + lane * 8) = ov;
    } else {
        f32x4 o0 = {o[0], o[1], o[2], o[3]};
        f32x4 o1 = {o[4], o[5], o[6], o[7]};
        *(f32x4*)(outf + row * 512 + lane * 8) = o0;
        *(f32x4*)(outf + row * 512 + lane * 8 + 4) = o1;
    }
}

// ---------------- MFMA GEMM: C[M,N] = A[M,K](bf16) @ BT[N,K](bf16) ----------------
// BM x 128 tile, BK=32, 3-slot LDS ring, SINGLE barrier per K-step:
//   vmcnt(LPS) -> barrier -> stage(s+2 into slot s-1) -> ds_read slot s -> MFMA
// RAW: each wave waits its own vmcnt before the barrier, so after the barrier
//   slot s is fully resident for everyone. FIFO makes vmcnt(LPS) drain
//   stage(s) while stage(s+1)'s LPS loads stay in flight across the barrier.
// WAR: readers of slot s-1 completed (MFMA lgkm dependency) before reaching
//   barrier(s); stage(s+2) overwrites slot s-1 only after barrier(s).
// LDS swizzle: chunk ^= (row>>1)&3 on 64B rows; linear dest + pre-swizzled src.
// Grid: 1-D, bijective XCD swizzle, N-FASTEST (A >> B for all our GEMMs:
// consecutive blocks share the L2-resident B-panel; A panels fetched once).
// EPI: 1 = qkv -> bf16 out, phi on cols<1024
//      2 = residual add into Cf
//      3 = +bias, gelu, bf16 out
//      4 = +bias, residual add into Cf
template<int EPI, int K, int BM>
__global__ __launch_bounds__(256, 4) void gemm_bt(
    const __bf16* __restrict__ A, const __bf16* __restrict__ BT,
    float* __restrict__ Cf, __bf16* __restrict__ Cb,
    const float* __restrict__ bias, int N, int nbn) {
    constexpr int NT = K / 32;
    constexpr int AL = BM / 64;            // A loads per thread per step
    constexpr int LPS = AL + 2;            // total loads per thread per step
    constexpr int NREP = (BM == 128) ? 4 : 2;
    __shared__ __align__(16) __bf16 Asm[3][BM * 32];
    __shared__ __align__(16) __bf16 Bsm[3][128 * 32];
    const int t = threadIdx.x;
    const int lane = t & 63;
    const int wave = t >> 6;
    const int wr = (BM == 128) ? (wave >> 1) : 0;
    const int wc = (BM == 128) ? (wave & 1) : wave;
    const int nblk = gridDim.x;
    const int q = nblk >> 3, r = nblk & 7;
    const int xcd = blockIdx.x & 7, loc = blockIdx.x >> 3;
    const int swz = (xcd < r ? xcd * (q + 1) : r * (q + 1) + (xcd - r) * q) + loc;
    const int m0 = (swz / nbn) * BM, n0 = (swz % nbn) * 128;   // n-fastest
    const int fr = lane & 15, fc = lane >> 4;

    const __bf16* Aps[AL];
    const __bf16* Bps[2];
    int aslot[AL], bslot[2];
    #pragma unroll
    for (int j = 0; j < AL; j++) {
        int slot = t + 256 * j;
        int row = slot >> 2, cp = slot & 3;
        int sc = cp ^ ((row >> 1) & 3);
        Aps[j] = A + (size_t)(m0 + row) * K + sc * 8;
        aslot[j] = slot * 8;
    }
    #pragma unroll
    for (int j = 0; j < 2; j++) {
        int slot = t + 256 * j;
        int row = slot >> 2, cp = slot & 3;
        int sc = cp ^ ((row >> 1) & 3);
        Bps[j] = BT + (size_t)(n0 + row) * K + sc * 8;
        bslot[j] = slot * 8;
    }

    f32x4 acc[4][NREP];
    #pragma unroll
    for (int m = 0; m < 4; m++)
        #pragma unroll
        for (int n = 0; n < NREP; n++)
            acc[m][n] = (f32x4){0.f, 0.f, 0.f, 0.f};

    auto stage = [&](int koff, __bf16* Ad, __bf16* Bd) {
        #pragma unroll
        for (int j = 0; j < AL; j++) GLOAD16(Aps[j] + koff, Ad + aslot[j]);
        #pragma unroll
        for (int j = 0; j < 2; j++) GLOAD16(Bps[j] + koff, Bd + bslot[j]);
    };

    stage(0, Asm[0], Bsm[0]);
    stage(32, Asm[1], Bsm[1]);

    for (int s = 0; s < NT; s++) {
        if (s + 1 < NT) {
            asm volatile("s_waitcnt vmcnt(%0)" :: "i"(LPS) : "memory");  // slot s landed
        } else {
            asm volatile("s_waitcnt vmcnt(0)" ::: "memory");
        }
        __builtin_amdgcn_s_barrier();
        if (s + 2 < NT) {
            int sl = (s + 2) % 3;
            stage((s + 2) * 32, Asm[sl], Bsm[sl]);   // overwrites slot s-1 (readers done)
        }
        const __bf16* Ac = Asm[s % 3];
        const __bf16* Bc = Bsm[s % 3];

        bf16x8 af[4], bfr[NREP];
        #pragma unroll
        for (int m = 0; m < 4; m++) {
            int ra = ((BM == 128) ? wr * 64 : 0) + m * 16 + fr;
            af[m] = *(const bf16x8*)(Ac + ra * 32 + ((fc ^ ((ra >> 1) & 3)) << 3));
        }
        #pragma unroll
        for (int n = 0; n < NREP; n++) {
            int rb = wc * (16 * NREP) + n * 16 + fr;
            bfr[n] = *(const bf16x8*)(Bc + rb * 32 + ((fc ^ ((rb >> 1) & 3)) << 3));
        }
        __builtin_amdgcn_s_setprio(1);
        #pragma unroll
        for (int m = 0; m < 4; m++)
            #pragma unroll
            for (int n = 0; n < NREP; n++)
                acc[m][n] = __builtin_amdgcn_mfma_f32_16x16x32_bf16(af[m], bfr[n], acc[m][n], 0, 0, 0);
        __builtin_amdgcn_s_setprio(0);
    }

    const int cr = (lane >> 4) * 4;
    const int cc = lane & 15;
    #pragma unroll
    for (int m = 0; m < 4; m++) {
        #pragma unroll
        for (int n = 0; n < NREP; n++) {
            #pragma unroll
            for (int r2 = 0; r2 < 4; r2++) {
                int grow = m0 + ((BM == 128) ? wr * 64 : 0) + m * 16 + cr + r2;
                int gcol = n0 + wc * (16 * NREP) + n * 16 + cc;
                size_t idx = (size_t)grow * N + gcol;
                float val = acc[m][n][r2];
                if (EPI == 1) {
                    if (gcol < 1024) val = fmaxf(val, 0.f) + 1e-3f;
                    Cb[idx] = (__bf16)val;
                } else if (EPI == 2) {
                    Cf[idx] += val;
                } else if (EPI == 3) {
                    val += bias[gcol];
                    Cb[idx] = (__bf16)gelu_tanh(val);
                } else if (EPI == 4) {
                    Cf[idx] += val + bias[gcol];
                } else {
                    Cf[idx] = val;
                }
            }
        }
    }
}

// ---------------- kv partial: per (b,h,chunk of 128 rows) 64x64 + pksum ----------------
__global__ __launch_bounds__(256) void kv_partial(const __bf16* __restrict__ qkvb,
                                                  float* __restrict__ part) {
    int bh = blockIdx.x;           // 32
    int chunk = blockIdx.y;        // 32 chunks of 128 rows
    int b = bh >> 3, hh = bh & 7;
    int t = threadIdx.x;
    int f = t & 63, eg = t >> 6;   // e-base = eg*16
    size_t base = ((size_t)b * SEQ + (size_t)chunk * 128) * 1536;
    const __bf16* kcol = qkvb + base + 512 + hh * 64 + f;
    const __bf16* vrow = qkvb + base + 1024 + hh * 64 + eg * 16;
    float psum = 0.f;
    f32x4 a0 = {0.f,0.f,0.f,0.f}, a1 = a0, a2 = a0, a3 = a0;
    for (int s = 0; s < 128; s++) {
        size_t o = (size_t)s * 1536;
        float pk = (float)kcol[o];
        psum += pk;
        bf16x8 w0 = *(const bf16x8*)(vrow + o);
        bf16x8 w1 = *(const bf16x8*)(vrow + o + 8);
        #pragma unroll
        for (int j = 0; j < 4; j++) {
            a0[j] += (float)w0[j]     * pk;
            a1[j] += (float)w0[4 + j] * pk;
            a2[j] += (float)w1[j]     * pk;
            a3[j] += (float)w1[4 + j] * pk;
        }
    }
    float* dst = part + ((size_t)chunk * 32 + bh) * 4160 + (size_t)f * 65 + eg * 16;
    #pragma unroll
    for (int j = 0; j < 4; j++) { dst[j] = a0[j]; dst[4+j] = a1[j]; dst[8+j] = a2[j]; dst[12+j] = a3[j]; }
    if (eg == 0) dst[64] = psum;   // pksum slot
}

__global__ void kv_reduce(const float* __restrict__ part, float* __restrict__ kvfin) {
    int i = blockIdx.x * 256 + threadIdx.x;
    if (i >= 32 * 4160) return;
    float s = 0.f;
    #pragma unroll 8
    for (int c = 0; c < 32; c++) s += part[(size_t)c * (32 * 4160) + i];
    kvfin[i] = s;
}

// ---------------- num / den / divide -> attn (bf16), MFMA with den column ----
// Per block: (b,h) x 128-row chunk. PQ(128x64) @ [KV | ps | 0](64x80):
// n-tiles 0..3 = numerator cols, n-tile 4 col 64 = ps -> acc[.][4] IS den.
// den broadcast within wave via __shfl from lanes cc==0 (C layout: col 64).
// kvb stride 86 elems: fc row-steps land on distinct bank groups.
__global__ __launch_bounds__(256) void num_attn(const __bf16* __restrict__ qkvb,
                                                const float* __restrict__ kvfin,
                                                __bf16* __restrict__ attn) {
    __shared__ __bf16 kvb[64][86];
    int bh = blockIdx.x, chunk = blockIdx.y;   // 32 x 32
    int b = bh >> 3, hh = bh & 7;
    const float* src = kvfin + (size_t)bh * 4160;
    int t = threadIdx.x;
    for (int i = t; i < 4096; i += 256) {
        int f = i >> 6, e = i & 63;
        kvb[f][e] = (__bf16)src[f * 65 + e];
    }
    if (t < 64) {
        kvb[t][64] = (__bf16)src[t * 65 + 64];     // ps column
        #pragma unroll
        for (int e = 65; e < 80; e++) kvb[t][e] = (__bf16)0.f;
    }
    const int lane = t & 63, w = t >> 6;
    const int fr = lane & 15, fc = lane >> 4;
    size_t rowbase = (size_t)b * SEQ + (size_t)chunk * 128 + w * 32;
    bf16x8 a[2][2];
    #pragma unroll
    for (int rt = 0; rt < 2; rt++)
        #pragma unroll
        for (int ks = 0; ks < 2; ks++)
            a[rt][ks] = *(const bf16x8*)(qkvb + (rowbase + rt * 16 + fr) * 1536 + hh * 64 + ks * 32 + fc * 8);
    __syncthreads();   // kvb visible
    bf16x8 bfrag[5][2];
    #pragma unroll
    for (int n = 0; n < 5; n++)
        #pragma unroll
        for (int ks = 0; ks < 2; ks++) {
            bf16x8 bv;
            #pragma unroll
            for (int j = 0; j < 8; j++) bv[j] = kvb[ks * 32 + fc * 8 + j][n * 16 + fr];
            bfrag[n][ks] = bv;
        }
    f32x4 acc[2][5];
    #pragma unroll
    for (int rt = 0; rt < 2; rt++)
        #pragma unroll
        for (int n = 0; n < 5; n++)
            acc[rt][n] = (f32x4){0.f, 0.f, 0.f, 0.f};
    #pragma unroll
    for (int ks = 0; ks < 2; ks++)
        #pragma unroll
        for (int rt = 0; rt < 2; rt++)
            #pragma unroll
            for (int n = 0; n < 5; n++)
                acc[rt][n] = __builtin_amdgcn_mfma_f32_16x16x32_bf16(a[rt][ks], bfrag[n][ks], acc[rt][n], 0, 0, 0);
    const int cr = (lane >> 4) * 4, cc = lane & 15;
    #pragma unroll
    for (int rt = 0; rt < 2; rt++) {
        float rdv[4];
        #pragma unroll
        for (int r2 = 0; r2 < 4; r2++)
            rdv[r2] = 1.f / __shfl(acc[rt][4][r2], lane & 48);   // den from cc==0 lane, same rows
        #pragma unroll
        for (int r2 = 0; r2 < 4; r2++) {
            int lr = w * 32 + rt * 16 + cr + r2;
            size_t grow = (size_t)b * SEQ + (size_t)chunk * 128 + lr;
            #pragma unroll
            for (int n = 0; n < 4; n++)
                attn[grow * 512 + hh * 64 + n * 16 + cc] = (__bf16)(acc[rt][n][r2] * rdv[r2]);
        }
    }
}

extern "C" void kernel_launch(void* const* d_in, const int* in_sizes, int n_in,
                              void* d_out, int out_size, void* d_ws, size_t ws_size,
                              hipStream_t stream) {
    const int*   tokens = (const int*)d_in[0];
    const float* embed  = (const float*)d_in[1];
    const float* Wq     = (const float*)d_in[2];
    const float* Wk     = (const float*)d_in[3];
    const float* Wv     = (const float*)d_in[4];
    const float* Wo     = (const float*)d_in[5];
    const float* ln1_s  = (const float*)d_in[6];
    const float* ln1_b  = (const float*)d_in[7];
    const float* W1     = (const float*)d_in[8];
    const float* b1     = (const float*)d_in[9];
    const float* W2     = (const float*)d_in[10];
    const float* b2     = (const float*)d_in[11];
    const float* ln2_s  = (const float*)d_in[12];
    const float* ln2_b  = (const float*)d_in[13];
    const float* lnf_s  = (const float*)d_in[14];
    const float* lnf_b  = (const float*)d_in[15];
    float* out = (float*)d_out;

    float* ws = (float*)d_ws;
    size_t off = 0;
    float* pos = ws;               off += 2097152;            // 4096*512 f32
    float* x   = ws + off;         off += 8388608;            // 16384*512 f32
    __bf16* h    = (__bf16*)(ws + off); off += 4194304;       // 16384*512 bf16
    __bf16* attn = (__bf16*)(ws + off); off += 4194304;       // 16384*512 bf16
    __bf16* qkvb = (__bf16*)(ws + off);                       // 16384*1536 bf16
    __bf16* hid  = (__bf16*)(ws + off); off += 16777216;      // 16384*2048 bf16 (union, serialized)
    float* kvpart = ws + off;      off += 32 * 32 * 4160;     // partials (32 chunks)
    float* kvfin  = ws + off;      off += 32 * 4160;
    __bf16* wbuf  = (__bf16*)(ws + off);                      // 6 * 3145728 bf16

    pos_kernel<<<4096, 256, 0, stream>>>(pos);
    transpose_bf16<<<dim3(16, 16, 6), dim3(32, 8), 0, stream>>>(Wq, wbuf,          512, 512,  262144, 3145728);
    transpose_bf16<<<dim3(16, 16, 6), dim3(32, 8), 0, stream>>>(Wk, wbuf + 262144, 512, 512,  262144, 3145728);
    transpose_bf16<<<dim3(16, 16, 6), dim3(32, 8), 0, stream>>>(Wv, wbuf + 524288, 512, 512,  262144, 3145728);
    transpose_bf16<<<dim3(16, 16, 6), dim3(32, 8), 0, stream>>>(Wo, wbuf + 786432, 512, 512,  262144, 3145728);
    transpose_bf16<<<dim3(64, 16, 6), dim3(32, 8), 0, stream>>>(W1, wbuf + 1048576, 512, 2048, 1048576, 3145728);
    transpose_bf16<<<dim3(16, 64, 6), dim3(32, 8), 0, stream>>>(W2, wbuf + 2097152, 2048, 512, 1048576, 3145728);
    embed_kernel<<<16384, 128, 0, stream>>>(tokens, embed, pos, x);

    for (int l = 0; l < 6; l++) {
        const __bf16* wl = wbuf + (size_t)l * 3145728;
        ln_kernel<1><<<4096, 256, 0, stream>>>(x, ln1_s + l * 512, ln1_b + l * 512, h, nullptr);
        gemm_bt<1, 512, 128><<<1536, 256, 0, stream>>>(h, wl, nullptr, qkvb, nullptr, 1536, 12);
        kv_partial<<<dim3(32, 32), 256, 0, stream>>>(qkvb, kvpart);
        kv_reduce<<<520, 256, 0, stream>>>(kvpart, kvfin);
        num_attn<<<dim3(32, 32), 256, 0, stream>>>(qkvb, kvfin, attn);
        gemm_bt<2, 512, 64><<<1024, 256, 0, stream>>>(attn, wl + 786432, x, nullptr, nullptr, 512, 4);
        ln_kernel<1><<<4096, 256, 0, stream>>>(x, ln2_s + l * 512, ln2_b + l * 512, h, nullptr);
        gemm_bt<3, 512, 128><<<2048, 256, 0, stream>>>(h, wl + 1048576, nullptr, hid, b1 + (size_t)l * 2048, 2048, 16);
        gemm_bt<4, 2048, 64><<<1024, 256, 0, stream>>>(hid, wl + 2097152, x, nullptr, b2 + (size_t)l * 512, 512, 4);
    }
    ln_kernel<0><<<4096, 256, 0, stream>>>(x, lnf_s, lnf_b, nullptr, out);
}